// Round 14
// baseline (50.147 us; speedup 1.0000x reference)
//
#include <hip/hip_runtime.h>
#include <hip/hip_bf16.h>
#include <math.h>

#define D_DIM 128
#define R_DIM 64
#define T_DIM 2048
#define B_DIM 8
#define NS 4                       // split-K factor over the s dimension
#define SCHUNK (T_DIM / NS)        // 512
#define SBLK 32                    // s-tile per iteration
#define NIT (SCHUNK / SBLK)        // 16
#define KE_CONST (0.08838834764831845f * 1.4426950408889634f)  // 1/sqrt(128) * log2(e)

typedef __attribute__((ext_vector_type(8))) short bf16x8;
typedef __attribute__((ext_vector_type(4))) short s16x4;
typedef __attribute__((ext_vector_type(4))) float f32x4;
typedef __attribute__((ext_vector_type(16))) float f32x16;

__device__ inline unsigned short f2bf(float f) {
  union { float f; unsigned int u; } v; v.f = f;
  return (unsigned short)((v.u + 0x7FFFu + ((v.u >> 16) & 1u)) >> 16);
}
__device__ inline float bf2f(unsigned short u) {
  union { unsigned int u; float f; } v; v.u = ((unsigned int)u) << 16;
  return v.f;
}
// packed RNE f32->bf16 pair: low half = lo, high half = hi (T12 recipe)
__device__ inline unsigned int cvt_pk_bf16(float lo, float hi) {
  unsigned int r;
  asm("v_cvt_pk_bf16_f32 %0, %1, %2" : "=v"(r) : "v"(lo), "v"(hi));
  return r;
}
// v_permlane32_swap_b32: lane l<32: a'=a, b'=a[l+32]; lane l>=32: a'=b[l-32], b'=b.
__device__ inline void permswap(unsigned int& a, unsigned int& b) {
  asm("v_permlane32_swap_b32 %0, %1" : "+v"(a), "+v"(b));
}

// async global->LDS, 16B per lane; LDS dest = wave-uniform base + lane*16
__device__ inline void async16(const short* l, const unsigned short* g) {
  __builtin_amdgcn_global_load_lds(
      (const __attribute__((address_space(1))) unsigned int*)g,
      (__attribute__((address_space(3))) unsigned int*)l, 16, 0, 0);
}

// ---------------- Kernel A: S = W W^T / sqrt(D*R), bf16, FRAGMENT layout ----------------
// Layout matches k_prep's B-frag read: Sb[((dc*4+kc)*64 + lane)*8 + j] with
// lane = g*16+c holding S[dc*16+c][kc*32+g*8+j].  (R12-verified)
__global__ void k_s(const float* __restrict__ W, unsigned short* __restrict__ Sb) {
  int gid = blockIdx.x * 256 + threadIdx.x;
  int i = gid >> 7, j = gid & 127;
  const float* wi = W + i * R_DIM;
  const float* wj = W + j * R_DIM;
  float acc = 0.f;
#pragma unroll 8
  for (int r = 0; r < R_DIM; ++r) acc += wi[r] * wj[r];
  int off = (((i >> 4) * 4 + (j >> 5)) * 64 + ((j & 31) >> 3) * 16 + (i & 15)) * 8 + (j & 7);
  Sb[off] = f2bf(acc * 0.011048543456039806f);  // 1/sqrt(128*64)
}

// ---------------- Kernel B: MFMA Q = X*S, outputs in k_attn frag layout ----------------
// Qb frag layout (R12-verified):
// Qb[((b*64 + t/32)*8 + dc)*512 + ((d>>3 & 1)*32 + (t&31))*8 + (d&7)], d = dc*16 + c.
__global__ void __launch_bounds__(128) k_prep(
    const float* __restrict__ X, const unsigned short* __restrict__ Sb,
    unsigned short* __restrict__ Qb, unsigned short* __restrict__ Xb,
    unsigned short* __restrict__ Xt, float* __restrict__ part) {
  const int tid = threadIdx.x;
  const int w = tid >> 6, lane = tid & 63;
  const int g = lane >> 4, c = lane & 15;
  const int b = blockIdx.y;
  const int t0 = blockIdx.x * 32;
  const int tw = t0 + w * 16;           // this wave's 16 rows

  __shared__ __align__(16) short xbT[D_DIM * 32];   // [e][t-local], 8 KB
  __shared__ float red[2];

  // load X rows, cvt to bf16 frags, write Xb, fill xbT transpose
  union FU { unsigned int wd[4]; bf16x8 v; };
  bf16x8 xf[4];
#pragma unroll
  for (int kc = 0; kc < 4; ++kc) {
    const float* xp = X + ((size_t)(b * T_DIM + tw + c)) * D_DIM + kc * 32 + g * 8;
    f32x4 a = *(const f32x4*)xp;
    f32x4 bb = *(const f32x4*)(xp + 4);
    FU f;
    f.wd[0] = cvt_pk_bf16(a[0], a[1]);
    f.wd[1] = cvt_pk_bf16(a[2], a[3]);
    f.wd[2] = cvt_pk_bf16(bb[0], bb[1]);
    f.wd[3] = cvt_pk_bf16(bb[2], bb[3]);
    xf[kc] = f.v;
    *(bf16x8*)(Xb + ((size_t)(b * T_DIM + tw + c)) * D_DIM + kc * 32 + g * 8) = f.v;
#pragma unroll
    for (int jw = 0; jw < 4; ++jw) {
      unsigned int wv = f.wd[jw];
      int e = kc * 32 + g * 8 + jw * 2;
      xbT[(e + 0) * 32 + w * 16 + c] = (short)wv;
      xbT[(e + 1) * 32 + w * 16 + c] = (short)(wv >> 16);
    }
  }

  // MFMA: acc[dc] = X(16 rows) * S, B-frags COALESCED from frag-layout Sb (L2-hot)
  f32x4 acc[8];
#pragma unroll
  for (int dc = 0; dc < 8; ++dc) acc[dc] = (f32x4){0.f, 0.f, 0.f, 0.f};
#pragma unroll
  for (int dc = 0; dc < 8; ++dc) {
    bf16x8 sf[4];
#pragma unroll
    for (int kc = 0; kc < 4; ++kc)
      sf[kc] = *(const bf16x8*)(Sb + ((size_t)(dc * 4 + kc) * 64 + lane) * 8);
#pragma unroll
    for (int kc = 0; kc < 4; ++kc)
      acc[dc] = __builtin_amdgcn_mfma_f32_16x16x32_bf16(xf[kc], sf[kc], acc[dc], 0, 0, 0);
  }

  __syncthreads();   // xbT complete (both waves)

  // trace partial (unscaled) + store Q pre-scaled by KE as bf16 in attn-frag layout
  float trp = 0.f;
#pragma unroll
  for (int dc = 0; dc < 8; ++dc)
#pragma unroll
    for (int r = 0; r < 4; ++r) {
      float q = acc[dc][r];
      float x = bf2f((unsigned short)xbT[(dc * 16 + c) * 32 + w * 16 + g * 4 + r]);
      trp += q * x;
      int t = tw + g * 4 + r;
      size_t qoff = (((size_t)(b * 64 + (t >> 5)) * 8 + dc) * 512 +
                     ((c >> 3) * 32 + (t & 31)) * 8 + (c & 7));
      Qb[qoff] = (unsigned short)cvt_pk_bf16(q * KE_CONST, 0.f);
    }

  // write Xt from xbT: 4 passes x 32 rows, b128 in / b128 out
#pragma unroll
  for (int p = 0; p < 4; ++p) {
    int row = p * 32 + (tid >> 2);
    bf16x8 v = *(const bf16x8*)&xbT[row * 32 + (tid & 3) * 8];
    *(bf16x8*)(Xt + ((size_t)(b * D_DIM + row)) * T_DIM + t0 + (tid & 3) * 8) = v;
  }

  // reduce trace partial: wave shuffle -> cross-wave via LDS
  trp += __shfl_xor(trp, 1); trp += __shfl_xor(trp, 2);
  trp += __shfl_xor(trp, 4); trp += __shfl_xor(trp, 8);
  trp += __shfl_xor(trp, 16); trp += __shfl_xor(trp, 32);
  if (lane == 0) red[w] = trp;
  __syncthreads();
  if (tid == 0) part[b * 64 + blockIdx.x] = red[0] + red[1];
}

// ---------------- Kernel C: flash attention, 4-buffer 2-deep pipeline ----------------
// R13 + T3/T4 full form: 4 LDS buffers, prefetch distance 2, s_waitcnt vmcnt(8)
// (tiles i+1,i+2 = 8 newest vmem ops stay in flight; tile i resident by in-order
// vmcnt retirement), ONE barrier per iter (safe with >=3-deep buffering: a wave
// staging buf (i+2)&3 passed B(i-1) => all waves completed iter i-2 = last
// readers of that buf). s_setprio(1) around MFMA cluster (T5).
__global__ void __launch_bounds__(256, 2) k_attn(
    const unsigned short* __restrict__ Qb, const unsigned short* __restrict__ Xb,
    const unsigned short* __restrict__ Xt, const float* __restrict__ part,
    unsigned short* __restrict__ accp, float* __restrict__ rsp) {
  const int tid = threadIdx.x;
  const int wave = tid >> 6, lane = tid & 63;
  const int tl = lane & 31;      // C/D col = t-local; A row = s-local
  const int h = lane >> 5;       // half-wave -> k_local*8
  // XCD-aware decomposition: bid&7 == b pins batch b's working set to one XCD.
  const int lin = blockIdx.x;
  const int b = lin & 7;
  const int kk = lin >> 3;
  const int ns = kk & 3;
  const int tile = kk >> 2;                      // 0..15
  const int t0w = tile * 128 + wave * 32;        // 32 q-rows per wave

  const unsigned short* Xbb = Xb + (size_t)b * T_DIM * D_DIM;
  const unsigned short* Xtb = Xt + (size_t)b * D_DIM * T_DIM;

  // inline trace reduction (per-wave redundant, L2-hot)
  float tv = part[b * 64 + lane];
  tv += __shfl_xor(tv, 1); tv += __shfl_xor(tv, 2);
  tv += __shfl_xor(tv, 4); tv += __shfl_xor(tv, 8);
  tv += __shfl_xor(tv, 16); tv += __shfl_xor(tv, 32);
  const float ctrK = tv * (1.0f / T_DIM) * KE_CONST;

  __shared__ __align__(16) short sKs[4][SBLK * D_DIM];   // 4 x 8 KB
  __shared__ __align__(16) short sVs[4][D_DIM * SBLK];   // 4 x 8 KB

  // swizzled ds_read offsets (shorts) — R11-verified
  int oK[8], oV[4][2];
#pragma unroll
  for (int kc = 0; kc < 8; ++kc)
    oK[kc] = tl * 128 + (((kc * 2 + h) ^ (tl & 15)) * 8);
#pragma unroll
  for (int dt = 0; dt < 4; ++dt)
#pragma unroll
    for (int sck = 0; sck < 2; ++sck)
      oV[dt][sck] = (dt * 32 + tl) * 32 + (((sck * 2 + h) ^ (tl & 3)) * 8);

  // Q B-frags, COALESCED from frag-layout Qb (R12-verified layout)
  const unsigned short* qbase =
      Qb + ((size_t)(b * 64 + tile * 4 + wave)) * 8 * 512;
  bf16x8 qf[8];
#pragma unroll
  for (int kc = 0; kc < 8; ++kc)
    qf[kc] = *(const bf16x8*)(qbase + (size_t)kc * 512 + lane * 8);

  f32x16 acc[4];
#pragma unroll
  for (int dt = 0; dt < 4; ++dt)
#pragma unroll
    for (int r = 0; r < 16; ++r) acc[dt][r] = 0.f;
  float denacc = 0.f;

  const int s_beg = ns * SCHUNK;

  // staging: 1024 16B chunks over 4 waves (2 K-issues + 2 V-issues per lane = 4 vmem)
  auto stage = [&](int buf, int sb) {
#pragma unroll
    for (int q = 0; q < 2; ++q) {
      int j = wave * 128 + q * 64 + lane;
      int row = j >> 4, sc = j & 15;
      int lc = sc ^ (row & 15);
      async16(&sKs[buf][(wave * 128 + q * 64) * 8],
              Xbb + (size_t)(sb + row) * D_DIM + lc * 8);
    }
#pragma unroll
    for (int q = 0; q < 2; ++q) {
      int j = wave * 128 + q * 64 + lane;
      int row = j >> 2, sc = j & 3;
      int lc = sc ^ (row & 3);
      async16(&sVs[buf][(wave * 128 + q * 64) * 8],
              Xtb + (size_t)row * T_DIM + sb + lc * 8);
    }
  };

  stage(0, s_beg);
  stage(1, s_beg + SBLK);

  for (int it = 0; it < NIT; ++it) {
    const int buf = it & 3;
    const int sb = s_beg + it * SBLK;

    // prefetch distance 2, counted waits: tile `it` resident after the wait,
    // tiles it+1/it+2 (the 8 newest staging ops) stay in flight.
    if (it < NIT - 2) {
      stage((it + 2) & 3, sb + 2 * SBLK);
      asm volatile("s_waitcnt vmcnt(8)" ::: "memory");
    } else if (it == NIT - 2) {
      asm volatile("s_waitcnt vmcnt(4)" ::: "memory");
    } else {
      asm volatile("s_waitcnt vmcnt(0)" ::: "memory");
    }
    __builtin_amdgcn_sched_barrier(0);
    __builtin_amdgcn_s_barrier();        // all waves: buf fully staged

    const short* kb = &sKs[buf][0];
    const short* vb = &sVs[buf][0];

    // LDS -> reg fragments (compiler inserts lgkmcnt before MFMA use)
    bf16x8 kf[8];
#pragma unroll
    for (int kc = 0; kc < 8; ++kc)
      kf[kc] = *(const bf16x8*)(kb + oK[kc]);
    bf16x8 vf[4][2];
#pragma unroll
    for (int dt = 0; dt < 4; ++dt)
#pragma unroll
      for (int sck = 0; sck < 2; ++sck)
        vf[dt][sck] = *(const bf16x8*)(vb + oV[dt][sck]);

    // ---- QK^T (swapped): out[s][t], t = tl lane-local ----
    f32x16 sc;
#pragma unroll
    for (int r = 0; r < 16; ++r) sc[r] = 0.f;
    __builtin_amdgcn_s_setprio(1);
#pragma unroll
    for (int kc = 0; kc < 8; ++kc)
      sc = __builtin_amdgcn_mfma_f32_32x32x16_bf16(kf[kc], qf[kc], sc, 0, 0, 0);
    __builtin_amdgcn_s_setprio(0);

    const bool isd = (sb == t0w);   // wave-uniform; both 32-aligned

    // ---- per s-chunk of 16: exp2 + in-register pack -> PV (R10-verified) ----
#pragma unroll
    for (int sck = 0; sck < 2; ++sck) {
      float p[8];
#pragma unroll
      for (int q = 0; q < 8; ++q) {
        int rowid = (q & 3) + 8 * (q >> 2) + 16 * sck + 4 * h;  // s_local
        float v = sc[sck * 8 + q];
        if (isd && rowid == tl) v -= ctrK;
        p[q] = exp2f(v);
        denacc += p[q];
      }
      unsigned int W0 = cvt_pk_bf16(p[0], p[1]);
      unsigned int W1 = cvt_pk_bf16(p[2], p[3]);
      unsigned int W2 = cvt_pk_bf16(p[4], p[5]);
      unsigned int W3 = cvt_pk_bf16(p[6], p[7]);
      permswap(W0, W2);
      permswap(W1, W3);
      union PU { unsigned int wd[4]; bf16x8 v; } pu;
      pu.wd[0] = W0; pu.wd[1] = W1; pu.wd[2] = W2; pu.wd[3] = W3;
      __builtin_amdgcn_s_setprio(1);
#pragma unroll
      for (int dt = 0; dt < 4; ++dt)
        acc[dt] = __builtin_amdgcn_mfma_f32_32x32x16_bf16(pu.v, vf[dt][sck],
                                                          acc[dt], 0, 0, 0);
      __builtin_amdgcn_s_setprio(0);
    }
    // no end-of-iter barrier: 4-deep buffering makes re-stage safe (see header)
  }

  // ---- den: own half + other half (same t, lane^32) ----
  float den = denacc + __shfl_xor(denacc, 32);
  if (lane < 32)
    rsp[(b * NS + ns) * T_DIM + t0w + lane] = den;

  // ---- write num partials (bf16), 32x32 C/D layout (R10-verified) ----
  const size_t pbase = ((size_t)(b * NS + ns)) * T_DIM * D_DIM;
#pragma unroll
  for (int dt = 0; dt < 4; ++dt)
#pragma unroll
    for (int r = 0; r < 16; ++r) {
      int rowid = (r & 3) + 8 * (r >> 2) + 4 * h;   // t_local
      accp[pbase + (size_t)(t0w + rowid) * D_DIM + dt * 32 + tl] =
          (unsigned short)cvt_pk_bf16(acc[dt][r], 0.f);
    }
}

// ---------------- Kernel D: combine split-K partials, normalize ----------------
// Same XCD swizzle: bid&7 == b, so accp/rsp reads hit the XCD-local L2.
__global__ void __launch_bounds__(256) k_comb(
    const unsigned short* __restrict__ accp, const float* __restrict__ rsp,
    float* __restrict__ out) {
  const int lin = blockIdx.x;
  const int b = lin & 7;
  const int kk = lin >> 3;                      // 0..255
  int ib = kk * 1024 + threadIdx.x * 4;         // element base within batch
  int d = ib & 127;
  int t = ib >> 7;
  float num0 = 0.f, num1 = 0.f, num2 = 0.f, num3 = 0.f, den = 0.f;
#pragma unroll
  for (int ns = 0; ns < NS; ++ns) {
    const unsigned short* p =
        accp + (((size_t)(b * NS + ns)) * T_DIM + t) * D_DIM + d;
    s16x4 v = *(const s16x4*)p;
    num0 += bf2f((unsigned short)v[0]);
    num1 += bf2f((unsigned short)v[1]);
    num2 += bf2f((unsigned short)v[2]);
    num3 += bf2f((unsigned short)v[3]);
    den += rsp[(b * NS + ns) * T_DIM + t];
  }
  float inv = 1.0f / den;
  f32x4 o = (f32x4){num0 * inv, num1 * inv, num2 * inv, num3 * inv};
  *(f32x4*)(out + ((size_t)b * T_DIM * D_DIM + ib)) = o;
}

extern "C" void kernel_launch(void* const* d_in, const int* in_sizes, int n_in,
                              void* d_out, int out_size, void* d_ws, size_t ws_size,
                              hipStream_t stream) {
  const float* X = (const float*)d_in[0];  // (8, 2048, 128) fp32
  const float* W = (const float*)d_in[1];  // (128, 64) fp32
  float* out = (float*)d_out;
  char* ws = (char*)d_ws;

  unsigned short* Sb = (unsigned short*)(ws);                 // 32 KB bf16 (frag layout)
  float* part        = (float*)(ws + 32768);                  // 2 KB
  unsigned short* Qb = (unsigned short*)(ws + 65536);         // 4 MB bf16 (frag layout)
  unsigned short* Xb = (unsigned short*)(ws + 65536 + 4194304);              // 4 MB
  unsigned short* Xt = (unsigned short*)(ws + 65536 + 2 * 4194304);          // 4 MB
  unsigned short* accp = (unsigned short*)(ws + 65536 + 3 * 4194304);        // 16 MB
  float* rsp         = (float*)(ws + 65536 + 3 * 4194304 + 16777216);        // 256 KB
  // total ws use: ~28.9 MB

  k_s<<<64, 256, 0, stream>>>(W, Sb);
  k_prep<<<dim3(T_DIM / 32, B_DIM), 128, 0, stream>>>(X, Sb, Qb, Xb, Xt, part);
  k_attn<<<(T_DIM / 128) * NS * B_DIM, 256, 0, stream>>>(Qb, Xb, Xt, part, accp, rsp);
  k_comb<<<B_DIM * 256, 256, 0, stream>>>(accp, rsp, out);
}

// Round 15
// 47.543 us; speedup vs baseline: 1.0548x; 1.0548x over previous
//
#include <hip/hip_runtime.h>
#include <hip/hip_bf16.h>
#include <math.h>

#define D_DIM 128
#define R_DIM 64
#define T_DIM 2048
#define B_DIM 8
#define NS 4                       // split-K factor over the s dimension
#define SCHUNK (T_DIM / NS)        // 512
#define SBLK 32                    // s-tile per iteration
#define NIT (SCHUNK / SBLK)        // 16
#define KE_CONST (0.08838834764831845f * 1.4426950408889634f)  // 1/sqrt(128) * log2(e)

typedef __attribute__((ext_vector_type(8))) short bf16x8;
typedef __attribute__((ext_vector_type(4))) short s16x4;
typedef __attribute__((ext_vector_type(4))) float f32x4;
typedef __attribute__((ext_vector_type(16))) float f32x16;

__device__ inline unsigned short f2bf(float f) {
  union { float f; unsigned int u; } v; v.f = f;
  return (unsigned short)((v.u + 0x7FFFu + ((v.u >> 16) & 1u)) >> 16);
}
__device__ inline float bf2f(unsigned short u) {
  union { unsigned int u; float f; } v; v.u = ((unsigned int)u) << 16;
  return v.f;
}
// packed RNE f32->bf16 pair: low half = lo, high half = hi (T12 recipe)
__device__ inline unsigned int cvt_pk_bf16(float lo, float hi) {
  unsigned int r;
  asm("v_cvt_pk_bf16_f32 %0, %1, %2" : "=v"(r) : "v"(lo), "v"(hi));
  return r;
}
// v_permlane32_swap_b32: lane l<32: a'=a, b'=a[l+32]; lane l>=32: a'=b[l-32], b'=b.
__device__ inline void permswap(unsigned int& a, unsigned int& b) {
  asm("v_permlane32_swap_b32 %0, %1" : "+v"(a), "+v"(b));
}

// async global->LDS, 16B per lane; LDS dest = wave-uniform base + lane*16
__device__ inline void async16(const short* l, const unsigned short* g) {
  __builtin_amdgcn_global_load_lds(
      (const __attribute__((address_space(1))) unsigned int*)g,
      (__attribute__((address_space(3))) unsigned int*)l, 16, 0, 0);
}

// ---------------- Kernel A: S = W W^T / sqrt(D*R), bf16, FRAGMENT layout ----------------
// Layout matches k_prep's B-frag read: Sb[((dc*4+kc)*64 + lane)*8 + j] with
// lane = g*16+c holding S[dc*16+c][kc*32+g*8+j].  (R12-verified)
__global__ void k_s(const float* __restrict__ W, unsigned short* __restrict__ Sb) {
  int gid = blockIdx.x * 256 + threadIdx.x;
  int i = gid >> 7, j = gid & 127;
  const float* wi = W + i * R_DIM;
  const float* wj = W + j * R_DIM;
  float acc = 0.f;
#pragma unroll 8
  for (int r = 0; r < R_DIM; ++r) acc += wi[r] * wj[r];
  int off = (((i >> 4) * 4 + (j >> 5)) * 64 + ((j & 31) >> 3) * 16 + (i & 15)) * 8 + (j & 7);
  Sb[off] = f2bf(acc * 0.011048543456039806f);  // 1/sqrt(128*64)
}

// ---------------- Kernel B: MFMA Q = X*S, outputs in k_attn frag layout ----------------
// Qb frag layout (R12-verified):
// Qb[((b*64 + t/32)*8 + dc)*512 + ((d>>3 & 1)*32 + (t&31))*8 + (d&7)], d = dc*16 + c.
__global__ void __launch_bounds__(128) k_prep(
    const float* __restrict__ X, const unsigned short* __restrict__ Sb,
    unsigned short* __restrict__ Qb, unsigned short* __restrict__ Xb,
    unsigned short* __restrict__ Xt, float* __restrict__ part) {
  const int tid = threadIdx.x;
  const int w = tid >> 6, lane = tid & 63;
  const int g = lane >> 4, c = lane & 15;
  const int b = blockIdx.y;
  const int t0 = blockIdx.x * 32;
  const int tw = t0 + w * 16;           // this wave's 16 rows

  __shared__ __align__(16) short xbT[D_DIM * 32];   // [e][t-local], 8 KB
  __shared__ float red[2];

  // load X rows, cvt to bf16 frags, write Xb, fill xbT transpose
  union FU { unsigned int wd[4]; bf16x8 v; };
  bf16x8 xf[4];
#pragma unroll
  for (int kc = 0; kc < 4; ++kc) {
    const float* xp = X + ((size_t)(b * T_DIM + tw + c)) * D_DIM + kc * 32 + g * 8;
    f32x4 a = *(const f32x4*)xp;
    f32x4 bb = *(const f32x4*)(xp + 4);
    FU f;
    f.wd[0] = cvt_pk_bf16(a[0], a[1]);
    f.wd[1] = cvt_pk_bf16(a[2], a[3]);
    f.wd[2] = cvt_pk_bf16(bb[0], bb[1]);
    f.wd[3] = cvt_pk_bf16(bb[2], bb[3]);
    xf[kc] = f.v;
    *(bf16x8*)(Xb + ((size_t)(b * T_DIM + tw + c)) * D_DIM + kc * 32 + g * 8) = f.v;
#pragma unroll
    for (int jw = 0; jw < 4; ++jw) {
      unsigned int wv = f.wd[jw];
      int e = kc * 32 + g * 8 + jw * 2;
      xbT[(e + 0) * 32 + w * 16 + c] = (short)wv;
      xbT[(e + 1) * 32 + w * 16 + c] = (short)(wv >> 16);
    }
  }

  // MFMA: acc[dc] = X(16 rows) * S, B-frags COALESCED from frag-layout Sb (L2-hot)
  f32x4 acc[8];
#pragma unroll
  for (int dc = 0; dc < 8; ++dc) acc[dc] = (f32x4){0.f, 0.f, 0.f, 0.f};
#pragma unroll
  for (int dc = 0; dc < 8; ++dc) {
    bf16x8 sf[4];
#pragma unroll
    for (int kc = 0; kc < 4; ++kc)
      sf[kc] = *(const bf16x8*)(Sb + ((size_t)(dc * 4 + kc) * 64 + lane) * 8);
#pragma unroll
    for (int kc = 0; kc < 4; ++kc)
      acc[dc] = __builtin_amdgcn_mfma_f32_16x16x32_bf16(xf[kc], sf[kc], acc[dc], 0, 0, 0);
  }

  __syncthreads();   // xbT complete (both waves)

  // trace partial (unscaled) + store Q pre-scaled by KE as bf16 in attn-frag layout
  float trp = 0.f;
#pragma unroll
  for (int dc = 0; dc < 8; ++dc)
#pragma unroll
    for (int r = 0; r < 4; ++r) {
      float q = acc[dc][r];
      float x = bf2f((unsigned short)xbT[(dc * 16 + c) * 32 + w * 16 + g * 4 + r]);
      trp += q * x;
      int t = tw + g * 4 + r;
      size_t qoff = (((size_t)(b * 64 + (t >> 5)) * 8 + dc) * 512 +
                     ((c >> 3) * 32 + (t & 31)) * 8 + (c & 7));
      Qb[qoff] = (unsigned short)cvt_pk_bf16(q * KE_CONST, 0.f);
    }

  // write Xt from xbT: 4 passes x 32 rows, b128 in / b128 out
#pragma unroll
  for (int p = 0; p < 4; ++p) {
    int row = p * 32 + (tid >> 2);
    bf16x8 v = *(const bf16x8*)&xbT[row * 32 + (tid & 3) * 8];
    *(bf16x8*)(Xt + ((size_t)(b * D_DIM + row)) * T_DIM + t0 + (tid & 3) * 8) = v;
  }

  // reduce trace partial: wave shuffle -> cross-wave via LDS
  trp += __shfl_xor(trp, 1); trp += __shfl_xor(trp, 2);
  trp += __shfl_xor(trp, 4); trp += __shfl_xor(trp, 8);
  trp += __shfl_xor(trp, 16); trp += __shfl_xor(trp, 32);
  if (lane == 0) red[w] = trp;
  __syncthreads();
  if (tid == 0) part[b * 64 + blockIdx.x] = red[0] + red[1];
}

// ---------------- Kernel C: flash attention, 4-buffer 2-deep pipeline, NO setprio ----------------
// R14 minus s_setprio (T5 is lockstep-hostile: m190). 4 LDS buffers, prefetch
// distance 2, s_waitcnt vmcnt(8) (tiles i+1,i+2 = 8 newest vmem ops in flight;
// tile i resident by in-order vmcnt retirement), ONE barrier per iter (safe:
// stage of buf (i+2)&3 issues after this wave passed B(i-1), and all waves'
// iter i-2 reads of that buf precede B(i-1)).
__global__ void __launch_bounds__(256, 2) k_attn(
    const unsigned short* __restrict__ Qb, const unsigned short* __restrict__ Xb,
    const unsigned short* __restrict__ Xt, const float* __restrict__ part,
    unsigned short* __restrict__ accp, float* __restrict__ rsp) {
  const int tid = threadIdx.x;
  const int wave = tid >> 6, lane = tid & 63;
  const int tl = lane & 31;      // C/D col = t-local; A row = s-local
  const int h = lane >> 5;       // half-wave -> k_local*8
  // XCD-aware decomposition: bid&7 == b pins batch b's working set to one XCD.
  const int lin = blockIdx.x;
  const int b = lin & 7;
  const int kk = lin >> 3;
  const int ns = kk & 3;
  const int tile = kk >> 2;                      // 0..15
  const int t0w = tile * 128 + wave * 32;        // 32 q-rows per wave

  const unsigned short* Xbb = Xb + (size_t)b * T_DIM * D_DIM;
  const unsigned short* Xtb = Xt + (size_t)b * D_DIM * T_DIM;

  // inline trace reduction (per-wave redundant, L2-hot)
  float tv = part[b * 64 + lane];
  tv += __shfl_xor(tv, 1); tv += __shfl_xor(tv, 2);
  tv += __shfl_xor(tv, 4); tv += __shfl_xor(tv, 8);
  tv += __shfl_xor(tv, 16); tv += __shfl_xor(tv, 32);
  const float ctrK = tv * (1.0f / T_DIM) * KE_CONST;

  __shared__ __align__(16) short sKs[4][SBLK * D_DIM];   // 4 x 8 KB
  __shared__ __align__(16) short sVs[4][D_DIM * SBLK];   // 4 x 8 KB

  // swizzled ds_read offsets (shorts) — R11-verified
  int oK[8], oV[4][2];
#pragma unroll
  for (int kc = 0; kc < 8; ++kc)
    oK[kc] = tl * 128 + (((kc * 2 + h) ^ (tl & 15)) * 8);
#pragma unroll
  for (int dt = 0; dt < 4; ++dt)
#pragma unroll
    for (int sck = 0; sck < 2; ++sck)
      oV[dt][sck] = (dt * 32 + tl) * 32 + (((sck * 2 + h) ^ (tl & 3)) * 8);

  // Q B-frags, COALESCED from frag-layout Qb (R12-verified layout)
  const unsigned short* qbase =
      Qb + ((size_t)(b * 64 + tile * 4 + wave)) * 8 * 512;
  bf16x8 qf[8];
#pragma unroll
  for (int kc = 0; kc < 8; ++kc)
    qf[kc] = *(const bf16x8*)(qbase + (size_t)kc * 512 + lane * 8);

  f32x16 acc[4];
#pragma unroll
  for (int dt = 0; dt < 4; ++dt)
#pragma unroll
    for (int r = 0; r < 16; ++r) acc[dt][r] = 0.f;
  float denacc = 0.f;

  const int s_beg = ns * SCHUNK;

  // staging: 1024 16B chunks over 4 waves (2 K-issues + 2 V-issues per lane = 4 vmem)
  auto stage = [&](int buf, int sb) {
#pragma unroll
    for (int q = 0; q < 2; ++q) {
      int j = wave * 128 + q * 64 + lane;
      int row = j >> 4, sc = j & 15;
      int lc = sc ^ (row & 15);
      async16(&sKs[buf][(wave * 128 + q * 64) * 8],
              Xbb + (size_t)(sb + row) * D_DIM + lc * 8);
    }
#pragma unroll
    for (int q = 0; q < 2; ++q) {
      int j = wave * 128 + q * 64 + lane;
      int row = j >> 2, sc = j & 3;
      int lc = sc ^ (row & 3);
      async16(&sVs[buf][(wave * 128 + q * 64) * 8],
              Xtb + (size_t)row * T_DIM + sb + lc * 8);
    }
  };

  stage(0, s_beg);
  stage(1, s_beg + SBLK);

  for (int it = 0; it < NIT; ++it) {
    const int buf = it & 3;
    const int sb = s_beg + it * SBLK;

    // prefetch distance 2, counted waits: tile `it` resident after the wait,
    // tiles it+1/it+2 (the 8 newest staging ops) stay in flight.
    if (it < NIT - 2) {
      stage((it + 2) & 3, sb + 2 * SBLK);
      asm volatile("s_waitcnt vmcnt(8)" ::: "memory");
    } else if (it == NIT - 2) {
      asm volatile("s_waitcnt vmcnt(4)" ::: "memory");
    } else {
      asm volatile("s_waitcnt vmcnt(0)" ::: "memory");
    }
    __builtin_amdgcn_sched_barrier(0);
    __builtin_amdgcn_s_barrier();        // all waves: buf fully staged

    const short* kb = &sKs[buf][0];
    const short* vb = &sVs[buf][0];

    // LDS -> reg fragments (compiler inserts lgkmcnt before MFMA use)
    bf16x8 kf[8];
#pragma unroll
    for (int kc = 0; kc < 8; ++kc)
      kf[kc] = *(const bf16x8*)(kb + oK[kc]);
    bf16x8 vf[4][2];
#pragma unroll
    for (int dt = 0; dt < 4; ++dt)
#pragma unroll
      for (int sck = 0; sck < 2; ++sck)
        vf[dt][sck] = *(const bf16x8*)(vb + oV[dt][sck]);

    // ---- QK^T (swapped): out[s][t], t = tl lane-local ----
    f32x16 sc;
#pragma unroll
    for (int r = 0; r < 16; ++r) sc[r] = 0.f;
#pragma unroll
    for (int kc = 0; kc < 8; ++kc)
      sc = __builtin_amdgcn_mfma_f32_32x32x16_bf16(kf[kc], qf[kc], sc, 0, 0, 0);

    const bool isd = (sb == t0w);   // wave-uniform; both 32-aligned

    // ---- per s-chunk of 16: exp2 + in-register pack -> PV (R10-verified) ----
#pragma unroll
    for (int sck = 0; sck < 2; ++sck) {
      float p[8];
#pragma unroll
      for (int q = 0; q < 8; ++q) {
        int rowid = (q & 3) + 8 * (q >> 2) + 16 * sck + 4 * h;  // s_local
        float v = sc[sck * 8 + q];
        if (isd && rowid == tl) v -= ctrK;
        p[q] = exp2f(v);
        denacc += p[q];
      }
      unsigned int W0 = cvt_pk_bf16(p[0], p[1]);
      unsigned int W1 = cvt_pk_bf16(p[2], p[3]);
      unsigned int W2 = cvt_pk_bf16(p[4], p[5]);
      unsigned int W3 = cvt_pk_bf16(p[6], p[7]);
      permswap(W0, W2);
      permswap(W1, W3);
      union PU { unsigned int wd[4]; bf16x8 v; } pu;
      pu.wd[0] = W0; pu.wd[1] = W1; pu.wd[2] = W2; pu.wd[3] = W3;
#pragma unroll
      for (int dt = 0; dt < 4; ++dt)
        acc[dt] = __builtin_amdgcn_mfma_f32_32x32x16_bf16(pu.v, vf[dt][sck],
                                                          acc[dt], 0, 0, 0);
    }
    // no end-of-iter barrier: 4-deep buffering makes re-stage safe (see header)
  }

  // ---- den: own half + other half (same t, lane^32) ----
  float den = denacc + __shfl_xor(denacc, 32);
  if (lane < 32)
    rsp[(b * NS + ns) * T_DIM + t0w + lane] = den;

  // ---- write num partials (bf16), 32x32 C/D layout (R10-verified) ----
  const size_t pbase = ((size_t)(b * NS + ns)) * T_DIM * D_DIM;
#pragma unroll
  for (int dt = 0; dt < 4; ++dt)
#pragma unroll
    for (int r = 0; r < 16; ++r) {
      int rowid = (r & 3) + 8 * (r >> 2) + 4 * h;   // t_local
      accp[pbase + (size_t)(t0w + rowid) * D_DIM + dt * 32 + tl] =
          (unsigned short)cvt_pk_bf16(acc[dt][r], 0.f);
    }
}

// ---------------- Kernel D: combine split-K partials, normalize ----------------
// Same XCD swizzle: bid&7 == b, so accp/rsp reads hit the XCD-local L2.
__global__ void __launch_bounds__(256) k_comb(
    const unsigned short* __restrict__ accp, const float* __restrict__ rsp,
    float* __restrict__ out) {
  const int lin = blockIdx.x;
  const int b = lin & 7;
  const int kk = lin >> 3;                      // 0..255
  int ib = kk * 1024 + threadIdx.x * 4;         // element base within batch
  int d = ib & 127;
  int t = ib >> 7;
  float num0 = 0.f, num1 = 0.f, num2 = 0.f, num3 = 0.f, den = 0.f;
#pragma unroll
  for (int ns = 0; ns < NS; ++ns) {
    const unsigned short* p =
        accp + (((size_t)(b * NS + ns)) * T_DIM + t) * D_DIM + d;
    s16x4 v = *(const s16x4*)p;
    num0 += bf2f((unsigned short)v[0]);
    num1 += bf2f((unsigned short)v[1]);
    num2 += bf2f((unsigned short)v[2]);
    num3 += bf2f((unsigned short)v[3]);
    den += rsp[(b * NS + ns) * T_DIM + t];
  }
  float inv = 1.0f / den;
  f32x4 o = (f32x4){num0 * inv, num1 * inv, num2 * inv, num3 * inv};
  *(f32x4*)(out + ((size_t)b * T_DIM * D_DIM + ib)) = o;
}

extern "C" void kernel_launch(void* const* d_in, const int* in_sizes, int n_in,
                              void* d_out, int out_size, void* d_ws, size_t ws_size,
                              hipStream_t stream) {
  const float* X = (const float*)d_in[0];  // (8, 2048, 128) fp32
  const float* W = (const float*)d_in[1];  // (128, 64) fp32
  float* out = (float*)d_out;
  char* ws = (char*)d_ws;

  unsigned short* Sb = (unsigned short*)(ws);                 // 32 KB bf16 (frag layout)
  float* part        = (float*)(ws + 32768);                  // 2 KB
  unsigned short* Qb = (unsigned short*)(ws + 65536);         // 4 MB bf16 (frag layout)
  unsigned short* Xb = (unsigned short*)(ws + 65536 + 4194304);              // 4 MB
  unsigned short* Xt = (unsigned short*)(ws + 65536 + 2 * 4194304);          // 4 MB
  unsigned short* accp = (unsigned short*)(ws + 65536 + 3 * 4194304);        // 16 MB
  float* rsp         = (float*)(ws + 65536 + 3 * 4194304 + 16777216);        // 256 KB
  // total ws use: ~28.9 MB

  k_s<<<64, 256, 0, stream>>>(W, Sb);
  k_prep<<<dim3(T_DIM / 32, B_DIM), 128, 0, stream>>>(X, Sb, Qb, Xb, Xt, part);
  k_attn<<<(T_DIM / 128) * NS * B_DIM, 256, 0, stream>>>(Qb, Xb, Xt, part, accp, rsp);
  k_comb<<<B_DIM * 256, 256, 0, stream>>>(accp, rsp, out);
}

// Round 16
// 46.804 us; speedup vs baseline: 1.0714x; 1.0158x over previous
//
#include <hip/hip_runtime.h>
#include <hip/hip_bf16.h>
#include <math.h>

#define D_DIM 128
#define R_DIM 64
#define T_DIM 2048
#define B_DIM 8
#define NS 4                       // split-K factor over the s dimension
#define SCHUNK (T_DIM / NS)        // 512
#define SBLK 32                    // s-tile per iteration
#define NIT (SCHUNK / SBLK)        // 16
#define KE_CONST (0.08838834764831845f * 1.4426950408889634f)  // 1/sqrt(128) * log2(e)

typedef __attribute__((ext_vector_type(8))) short bf16x8;
typedef __attribute__((ext_vector_type(4))) short s16x4;
typedef __attribute__((ext_vector_type(4))) float f32x4;
typedef __attribute__((ext_vector_type(16))) float f32x16;

__device__ inline unsigned short f2bf(float f) {
  union { float f; unsigned int u; } v; v.f = f;
  return (unsigned short)((v.u + 0x7FFFu + ((v.u >> 16) & 1u)) >> 16);
}
__device__ inline float bf2f(unsigned short u) {
  union { unsigned int u; float f; } v; v.u = ((unsigned int)u) << 16;
  return v.f;
}
// packed RNE f32->bf16 pair: low half = lo, high half = hi (T12 recipe)
__device__ inline unsigned int cvt_pk_bf16(float lo, float hi) {
  unsigned int r;
  asm("v_cvt_pk_bf16_f32 %0, %1, %2" : "=v"(r) : "v"(lo), "v"(hi));
  return r;
}
// v_permlane32_swap_b32: lane l<32: a'=a, b'=a[l+32]; lane l>=32: a'=b[l-32], b'=b.
__device__ inline void permswap(unsigned int& a, unsigned int& b) {
  asm("v_permlane32_swap_b32 %0, %1" : "+v"(a), "+v"(b));
}

// async global->LDS, 16B per lane; LDS dest = wave-uniform base + lane*16
__device__ inline void async16(const short* l, const unsigned short* g) {
  __builtin_amdgcn_global_load_lds(
      (const __attribute__((address_space(1))) unsigned int*)g,
      (__attribute__((address_space(3))) unsigned int*)l, 16, 0, 0);
}

// ---------------- Kernel A: S = W W^T / sqrt(D*R), bf16, FRAGMENT layout ----------------
// Layout matches k_prep's B-frag read: Sb[((dc*4+kc)*64 + lane)*8 + j] with
// lane = g*16+c holding S[dc*16+c][kc*32+g*8+j].  (R12-verified)
__global__ void k_s(const float* __restrict__ W, unsigned short* __restrict__ Sb) {
  int gid = blockIdx.x * 256 + threadIdx.x;
  int i = gid >> 7, j = gid & 127;
  const float* wi = W + i * R_DIM;
  const float* wj = W + j * R_DIM;
  float acc = 0.f;
#pragma unroll 8
  for (int r = 0; r < R_DIM; ++r) acc += wi[r] * wj[r];
  int off = (((i >> 4) * 4 + (j >> 5)) * 64 + ((j & 31) >> 3) * 16 + (i & 15)) * 8 + (j & 7);
  Sb[off] = f2bf(acc * 0.011048543456039806f);  // 1/sqrt(128*64)
}

// ---------------- Kernel B: MFMA Q = X*S, outputs in k_attn frag layout ----------------
// Qb frag layout (R12-verified):
// Qb[((b*64 + t/32)*8 + dc)*512 + ((d>>3 & 1)*32 + (t&31))*8 + (d&7)], d = dc*16 + c.
__global__ void __launch_bounds__(128) k_prep(
    const float* __restrict__ X, const unsigned short* __restrict__ Sb,
    unsigned short* __restrict__ Qb, unsigned short* __restrict__ Xb,
    unsigned short* __restrict__ Xt, float* __restrict__ part) {
  const int tid = threadIdx.x;
  const int w = tid >> 6, lane = tid & 63;
  const int g = lane >> 4, c = lane & 15;
  const int b = blockIdx.y;
  const int t0 = blockIdx.x * 32;
  const int tw = t0 + w * 16;           // this wave's 16 rows

  __shared__ __align__(16) short xbT[D_DIM * 32];   // [e][t-local], 8 KB
  __shared__ float red[2];

  // load X rows, cvt to bf16 frags, write Xb, fill xbT transpose
  union FU { unsigned int wd[4]; bf16x8 v; };
  bf16x8 xf[4];
#pragma unroll
  for (int kc = 0; kc < 4; ++kc) {
    const float* xp = X + ((size_t)(b * T_DIM + tw + c)) * D_DIM + kc * 32 + g * 8;
    f32x4 a = *(const f32x4*)xp;
    f32x4 bb = *(const f32x4*)(xp + 4);
    FU f;
    f.wd[0] = cvt_pk_bf16(a[0], a[1]);
    f.wd[1] = cvt_pk_bf16(a[2], a[3]);
    f.wd[2] = cvt_pk_bf16(bb[0], bb[1]);
    f.wd[3] = cvt_pk_bf16(bb[2], bb[3]);
    xf[kc] = f.v;
    *(bf16x8*)(Xb + ((size_t)(b * T_DIM + tw + c)) * D_DIM + kc * 32 + g * 8) = f.v;
#pragma unroll
    for (int jw = 0; jw < 4; ++jw) {
      unsigned int wv = f.wd[jw];
      int e = kc * 32 + g * 8 + jw * 2;
      xbT[(e + 0) * 32 + w * 16 + c] = (short)wv;
      xbT[(e + 1) * 32 + w * 16 + c] = (short)(wv >> 16);
    }
  }

  // MFMA: acc[dc] = X(16 rows) * S, B-frags COALESCED from frag-layout Sb (L2-hot)
  f32x4 acc[8];
#pragma unroll
  for (int dc = 0; dc < 8; ++dc) acc[dc] = (f32x4){0.f, 0.f, 0.f, 0.f};
#pragma unroll
  for (int dc = 0; dc < 8; ++dc) {
    bf16x8 sf[4];
#pragma unroll
    for (int kc = 0; kc < 4; ++kc)
      sf[kc] = *(const bf16x8*)(Sb + ((size_t)(dc * 4 + kc) * 64 + lane) * 8);
#pragma unroll
    for (int kc = 0; kc < 4; ++kc)
      acc[dc] = __builtin_amdgcn_mfma_f32_16x16x32_bf16(xf[kc], sf[kc], acc[dc], 0, 0, 0);
  }

  __syncthreads();   // xbT complete (both waves)

  // trace partial (unscaled) + store Q pre-scaled by KE as bf16 in attn-frag layout
  float trp = 0.f;
#pragma unroll
  for (int dc = 0; dc < 8; ++dc)
#pragma unroll
    for (int r = 0; r < 4; ++r) {
      float q = acc[dc][r];
      float x = bf2f((unsigned short)xbT[(dc * 16 + c) * 32 + w * 16 + g * 4 + r]);
      trp += q * x;
      int t = tw + g * 4 + r;
      size_t qoff = (((size_t)(b * 64 + (t >> 5)) * 8 + dc) * 512 +
                     ((c >> 3) * 32 + (t & 31)) * 8 + (c & 7));
      Qb[qoff] = (unsigned short)cvt_pk_bf16(q * KE_CONST, 0.f);
    }

  // write Xt from xbT: 4 passes x 32 rows, b128 in / b128 out
#pragma unroll
  for (int p = 0; p < 4; ++p) {
    int row = p * 32 + (tid >> 2);
    bf16x8 v = *(const bf16x8*)&xbT[row * 32 + (tid & 3) * 8];
    *(bf16x8*)(Xt + ((size_t)(b * D_DIM + row)) * T_DIM + t0 + (tid & 3) * 8) = v;
  }

  // reduce trace partial: wave shuffle -> cross-wave via LDS
  trp += __shfl_xor(trp, 1); trp += __shfl_xor(trp, 2);
  trp += __shfl_xor(trp, 4); trp += __shfl_xor(trp, 8);
  trp += __shfl_xor(trp, 16); trp += __shfl_xor(trp, 32);
  if (lane == 0) red[w] = trp;
  __syncthreads();
  if (tid == 0) part[b * 64 + blockIdx.x] = red[0] + red[1];
}

// ---------------- Kernel C: flash attention — R13-exact (best known) ----------------
// 4 waves x 32 t-rows, 512 blocks (2 blocks/CU). 2 LDS buffers, counted
// s_waitcnt vmcnt(4) (next tile's 4 staging ops stay in flight across the
// barrier), 2 barriers/iter. In-register P (cvt_pk + permlane32_swap). No
// setprio (lockstep-hostile, R14/R15 A/B).
__global__ void __launch_bounds__(256, 2) k_attn(
    const unsigned short* __restrict__ Qb, const unsigned short* __restrict__ Xb,
    const unsigned short* __restrict__ Xt, const float* __restrict__ part,
    unsigned short* __restrict__ accp, float* __restrict__ rsp) {
  const int tid = threadIdx.x;
  const int wave = tid >> 6, lane = tid & 63;
  const int tl = lane & 31;      // C/D col = t-local; A row = s-local
  const int h = lane >> 5;       // half-wave -> k_local*8
  // XCD-aware decomposition: bid&7 == b pins batch b's working set to one XCD.
  const int lin = blockIdx.x;
  const int b = lin & 7;
  const int kk = lin >> 3;
  const int ns = kk & 3;
  const int tile = kk >> 2;                      // 0..15
  const int t0w = tile * 128 + wave * 32;        // 32 q-rows per wave

  const unsigned short* Xbb = Xb + (size_t)b * T_DIM * D_DIM;
  const unsigned short* Xtb = Xt + (size_t)b * D_DIM * T_DIM;

  // inline trace reduction (per-wave redundant, L2-hot)
  float tv = part[b * 64 + lane];
  tv += __shfl_xor(tv, 1); tv += __shfl_xor(tv, 2);
  tv += __shfl_xor(tv, 4); tv += __shfl_xor(tv, 8);
  tv += __shfl_xor(tv, 16); tv += __shfl_xor(tv, 32);
  const float ctrK = tv * (1.0f / T_DIM) * KE_CONST;

  __shared__ __align__(16) short sKs[2][SBLK * D_DIM];   // 2 x 8 KB
  __shared__ __align__(16) short sVs[2][D_DIM * SBLK];   // 2 x 8 KB

  // swizzled ds_read offsets (shorts) — R11-verified
  int oK[8], oV[4][2];
#pragma unroll
  for (int kc = 0; kc < 8; ++kc)
    oK[kc] = tl * 128 + (((kc * 2 + h) ^ (tl & 15)) * 8);
#pragma unroll
  for (int dt = 0; dt < 4; ++dt)
#pragma unroll
    for (int sck = 0; sck < 2; ++sck)
      oV[dt][sck] = (dt * 32 + tl) * 32 + (((sck * 2 + h) ^ (tl & 3)) * 8);

  // Q B-frags, COALESCED from frag-layout Qb (R12-verified layout)
  const unsigned short* qbase =
      Qb + ((size_t)(b * 64 + tile * 4 + wave)) * 8 * 512;
  bf16x8 qf[8];
#pragma unroll
  for (int kc = 0; kc < 8; ++kc)
    qf[kc] = *(const bf16x8*)(qbase + (size_t)kc * 512 + lane * 8);

  f32x16 acc[4];
#pragma unroll
  for (int dt = 0; dt < 4; ++dt)
#pragma unroll
    for (int r = 0; r < 16; ++r) acc[dt][r] = 0.f;
  float denacc = 0.f;

  const int s_beg = ns * SCHUNK;

  // staging: 1024 16B chunks over 4 waves (2 K-issues + 2 V-issues per lane = 4 vmem)
  auto stage = [&](int buf, int sb) {
#pragma unroll
    for (int q = 0; q < 2; ++q) {
      int j = wave * 128 + q * 64 + lane;
      int row = j >> 4, sc = j & 15;
      int lc = sc ^ (row & 15);
      async16(&sKs[buf][(wave * 128 + q * 64) * 8],
              Xbb + (size_t)(sb + row) * D_DIM + lc * 8);
    }
#pragma unroll
    for (int q = 0; q < 2; ++q) {
      int j = wave * 128 + q * 64 + lane;
      int row = j >> 2, sc = j & 3;
      int lc = sc ^ (row & 3);
      async16(&sVs[buf][(wave * 128 + q * 64) * 8],
              Xtb + (size_t)row * T_DIM + sb + lc * 8);
    }
  };

  stage(0, s_beg);

  for (int it = 0; it < NIT; ++it) {
    const int buf = it & 1;
    const int sb = s_beg + it * SBLK;

    // issue next tile, then counted wait: own prior-tile (buf) issues complete,
    // the 4 just-issued (buf^1) stay in flight across the barrier.
    if (it < NIT - 1) {
      stage(buf ^ 1, sb + SBLK);
      asm volatile("s_waitcnt vmcnt(4)" ::: "memory");
    } else {
      asm volatile("s_waitcnt vmcnt(0)" ::: "memory");
    }
    __builtin_amdgcn_sched_barrier(0);
    __builtin_amdgcn_s_barrier();        // all waves: buf fully staged

    const short* kb = &sKs[buf][0];
    const short* vb = &sVs[buf][0];

    // LDS -> reg fragments (compiler inserts lgkmcnt before MFMA use)
    bf16x8 kf[8];
#pragma unroll
    for (int kc = 0; kc < 8; ++kc)
      kf[kc] = *(const bf16x8*)(kb + oK[kc]);
    bf16x8 vf[4][2];
#pragma unroll
    for (int dt = 0; dt < 4; ++dt)
#pragma unroll
      for (int sck = 0; sck < 2; ++sck)
        vf[dt][sck] = *(const bf16x8*)(vb + oV[dt][sck]);

    // ---- QK^T (swapped): out[s][t], t = tl lane-local ----
    f32x16 sc;
#pragma unroll
    for (int r = 0; r < 16; ++r) sc[r] = 0.f;
#pragma unroll
    for (int kc = 0; kc < 8; ++kc)
      sc = __builtin_amdgcn_mfma_f32_32x32x16_bf16(kf[kc], qf[kc], sc, 0, 0, 0);

    const bool isd = (sb == t0w);   // wave-uniform; both 32-aligned

    // ---- per s-chunk of 16: exp2 + in-register pack -> PV (R10-verified) ----
#pragma unroll
    for (int sck = 0; sck < 2; ++sck) {
      float p[8];
#pragma unroll
      for (int q = 0; q < 8; ++q) {
        int rowid = (q & 3) + 8 * (q >> 2) + 16 * sck + 4 * h;  // s_local
        float v = sc[sck * 8 + q];
        if (isd && rowid == tl) v -= ctrK;
        p[q] = exp2f(v);
        denacc += p[q];
      }
      unsigned int W0 = cvt_pk_bf16(p[0], p[1]);
      unsigned int W1 = cvt_pk_bf16(p[2], p[3]);
      unsigned int W2 = cvt_pk_bf16(p[4], p[5]);
      unsigned int W3 = cvt_pk_bf16(p[6], p[7]);
      permswap(W0, W2);
      permswap(W1, W3);
      union PU { unsigned int wd[4]; bf16x8 v; } pu;
      pu.wd[0] = W0; pu.wd[1] = W1; pu.wd[2] = W2; pu.wd[3] = W3;
#pragma unroll
      for (int dt = 0; dt < 4; ++dt)
        acc[dt] = __builtin_amdgcn_mfma_f32_32x32x16_bf16(pu.v, vf[dt][sck],
                                                          acc[dt], 0, 0, 0);
    }

    // all waves done reading buf before anyone re-stages it next iteration
    __builtin_amdgcn_s_barrier();
  }

  // ---- den: own half + other half (same t, lane^32) ----
  float den = denacc + __shfl_xor(denacc, 32);
  if (lane < 32)
    rsp[(b * NS + ns) * T_DIM + t0w + lane] = den;

  // ---- write num partials (bf16), 32x32 C/D layout (R10-verified) ----
  const size_t pbase = ((size_t)(b * NS + ns)) * T_DIM * D_DIM;
#pragma unroll
  for (int dt = 0; dt < 4; ++dt)
#pragma unroll
    for (int r = 0; r < 16; ++r) {
      int rowid = (r & 3) + 8 * (r >> 2) + 4 * h;   // t_local
      accp[pbase + (size_t)(t0w + rowid) * D_DIM + dt * 32 + tl] =
          (unsigned short)cvt_pk_bf16(acc[dt][r], 0.f);
    }
}

// ---------------- Kernel D: combine split-K partials, 8 elems/thread, b128 ----------------
// XCD swizzle: bid&7 == b so accp/rsp reads hit the XCD-local L2.
__global__ void __launch_bounds__(256) k_comb(
    const unsigned short* __restrict__ accp, const float* __restrict__ rsp,
    float* __restrict__ out) {
  const int lin = blockIdx.x;
  const int b = lin & 7;
  const int kk = lin >> 3;                      // 0..127
  int ib = kk * 2048 + threadIdx.x * 8;         // element base within batch
  int d = ib & 127;
  int t = ib >> 7;
  float num[8] = {0.f, 0.f, 0.f, 0.f, 0.f, 0.f, 0.f, 0.f};
  float den = 0.f;
#pragma unroll
  for (int ns = 0; ns < NS; ++ns) {
    const unsigned short* p =
        accp + (((size_t)(b * NS + ns)) * T_DIM + t) * D_DIM + d;
    bf16x8 v = *(const bf16x8*)p;
#pragma unroll
    for (int j = 0; j < 8; ++j) num[j] += bf2f((unsigned short)v[j]);
    den += rsp[(b * NS + ns) * T_DIM + t];
  }
  float inv = 1.0f / den;
  float* o = out + ((size_t)b * T_DIM * D_DIM + ib);
  f32x4 o0 = (f32x4){num[0] * inv, num[1] * inv, num[2] * inv, num[3] * inv};
  f32x4 o1 = (f32x4){num[4] * inv, num[5] * inv, num[6] * inv, num[7] * inv};
  *(f32x4*)(o + 0) = o0;
  *(f32x4*)(o + 4) = o1;
}

extern "C" void kernel_launch(void* const* d_in, const int* in_sizes, int n_in,
                              void* d_out, int out_size, void* d_ws, size_t ws_size,
                              hipStream_t stream) {
  const float* X = (const float*)d_in[0];  // (8, 2048, 128) fp32
  const float* W = (const float*)d_in[1];  // (128, 64) fp32
  float* out = (float*)d_out;
  char* ws = (char*)d_ws;

  unsigned short* Sb = (unsigned short*)(ws);                 // 32 KB bf16 (frag layout)
  float* part        = (float*)(ws + 32768);                  // 2 KB
  unsigned short* Qb = (unsigned short*)(ws + 65536);         // 4 MB bf16 (frag layout)
  unsigned short* Xb = (unsigned short*)(ws + 65536 + 4194304);              // 4 MB
  unsigned short* Xt = (unsigned short*)(ws + 65536 + 2 * 4194304);          // 4 MB
  unsigned short* accp = (unsigned short*)(ws + 65536 + 3 * 4194304);        // 16 MB
  float* rsp         = (float*)(ws + 65536 + 3 * 4194304 + 16777216);        // 256 KB
  // total ws use: ~28.9 MB

  k_s<<<64, 256, 0, stream>>>(W, Sb);
  k_prep<<<dim3(T_DIM / 32, B_DIM), 128, 0, stream>>>(X, Sb, Qb, Xb, Xt, part);
  k_attn<<<(T_DIM / 128) * NS * B_DIM, 256, 0, stream>>>(Qb, Xb, Xt, part, accp, rsp);
  k_comb<<<B_DIM * 128, 256, 0, stream>>>(accp, rsp, out);
}

// Round 17
// 44.963 us; speedup vs baseline: 1.1153x; 1.0410x over previous
//
#include <hip/hip_runtime.h>
#include <hip/hip_bf16.h>
#include <math.h>

#define D_DIM 128
#define R_DIM 64
#define T_DIM 2048
#define B_DIM 8
#define NS 4                       // split-K factor over the s dimension
#define SCHUNK (T_DIM / NS)        // 512
#define SBLK 32                    // s-tile per iteration
#define NIT (SCHUNK / SBLK)        // 16
#define KE_CONST (0.08838834764831845f * 1.4426950408889634f)  // 1/sqrt(128) * log2(e)

typedef __attribute__((ext_vector_type(8))) short bf16x8;
typedef __attribute__((ext_vector_type(4))) short s16x4;
typedef __attribute__((ext_vector_type(4))) float f32x4;
typedef __attribute__((ext_vector_type(16))) float f32x16;

__device__ inline unsigned short f2bf(float f) {
  union { float f; unsigned int u; } v; v.f = f;
  return (unsigned short)((v.u + 0x7FFFu + ((v.u >> 16) & 1u)) >> 16);
}
__device__ inline float bf2f(unsigned short u) {
  union { unsigned int u; float f; } v; v.u = ((unsigned int)u) << 16;
  return v.f;
}
// packed RNE f32->bf16 pair: low half = lo, high half = hi (T12 recipe)
__device__ inline unsigned int cvt_pk_bf16(float lo, float hi) {
  unsigned int r;
  asm("v_cvt_pk_bf16_f32 %0, %1, %2" : "=v"(r) : "v"(lo), "v"(hi));
  return r;
}
// v_permlane32_swap_b32: lane l<32: a'=a, b'=a[l+32]; lane l>=32: a'=b[l-32], b'=b.
__device__ inline void permswap(unsigned int& a, unsigned int& b) {
  asm("v_permlane32_swap_b32 %0, %1" : "+v"(a), "+v"(b));
}
// raw 2^x (input |x| small -> no libm edge handling needed)
__device__ inline float fexp2(float x) {
  float r;
  asm("v_exp_f32 %0, %1" : "=v"(r) : "v"(x));
  return r;
}

// async global->LDS, 16B per lane; LDS dest = wave-uniform base + lane*16
__device__ inline void async16(const short* l, const unsigned short* g) {
  __builtin_amdgcn_global_load_lds(
      (const __attribute__((address_space(1))) unsigned int*)g,
      (__attribute__((address_space(3))) unsigned int*)l, 16, 0, 0);
}

// ---------------- Kernel A: S = W W^T / sqrt(D*R), bf16, FRAGMENT layout ----------------
// Layout matches k_prep's B-frag read: Sb[((dc*4+kc)*64 + lane)*8 + j] with
// lane = g*16+c holding S[dc*16+c][kc*32+g*8+j].  (R12-verified)
__global__ void k_s(const float* __restrict__ W, unsigned short* __restrict__ Sb) {
  int gid = blockIdx.x * 256 + threadIdx.x;
  int i = gid >> 7, j = gid & 127;
  const float* wi = W + i * R_DIM;
  const float* wj = W + j * R_DIM;
  float acc = 0.f;
#pragma unroll 8
  for (int r = 0; r < R_DIM; ++r) acc += wi[r] * wj[r];
  int off = (((i >> 4) * 4 + (j >> 5)) * 64 + ((j & 31) >> 3) * 16 + (i & 15)) * 8 + (j & 7);
  Sb[off] = f2bf(acc * 0.011048543456039806f);  // 1/sqrt(128*64)
}

// ---------------- Kernel B: MFMA Q = X*S, outputs in k_attn frag layout ----------------
// Qb frag layout (R12-verified):
// Qb[((b*64 + t/32)*8 + dc)*512 + ((d>>3 & 1)*32 + (t&31))*8 + (d&7)], d = dc*16 + c.
__global__ void __launch_bounds__(128) k_prep(
    const float* __restrict__ X, const unsigned short* __restrict__ Sb,
    unsigned short* __restrict__ Qb, unsigned short* __restrict__ Xb,
    unsigned short* __restrict__ Xt, float* __restrict__ part) {
  const int tid = threadIdx.x;
  const int w = tid >> 6, lane = tid & 63;
  const int g = lane >> 4, c = lane & 15;
  const int b = blockIdx.y;
  const int t0 = blockIdx.x * 32;
  const int tw = t0 + w * 16;           // this wave's 16 rows

  __shared__ __align__(16) short xbT[D_DIM * 32];   // [e][t-local], 8 KB
  __shared__ float red[2];

  // load X rows, cvt to bf16 frags, write Xb, fill xbT transpose
  union FU { unsigned int wd[4]; bf16x8 v; };
  bf16x8 xf[4];
#pragma unroll
  for (int kc = 0; kc < 4; ++kc) {
    const float* xp = X + ((size_t)(b * T_DIM + tw + c)) * D_DIM + kc * 32 + g * 8;
    f32x4 a = *(const f32x4*)xp;
    f32x4 bb = *(const f32x4*)(xp + 4);
    FU f;
    f.wd[0] = cvt_pk_bf16(a[0], a[1]);
    f.wd[1] = cvt_pk_bf16(a[2], a[3]);
    f.wd[2] = cvt_pk_bf16(bb[0], bb[1]);
    f.wd[3] = cvt_pk_bf16(bb[2], bb[3]);
    xf[kc] = f.v;
    *(bf16x8*)(Xb + ((size_t)(b * T_DIM + tw + c)) * D_DIM + kc * 32 + g * 8) = f.v;
#pragma unroll
    for (int jw = 0; jw < 4; ++jw) {
      unsigned int wv = f.wd[jw];
      int e = kc * 32 + g * 8 + jw * 2;
      xbT[(e + 0) * 32 + w * 16 + c] = (short)wv;
      xbT[(e + 1) * 32 + w * 16 + c] = (short)(wv >> 16);
    }
  }

  // MFMA: acc[dc] = X(16 rows) * S, B-frags COALESCED from frag-layout Sb (L2-hot)
  f32x4 acc[8];
#pragma unroll
  for (int dc = 0; dc < 8; ++dc) acc[dc] = (f32x4){0.f, 0.f, 0.f, 0.f};
#pragma unroll
  for (int dc = 0; dc < 8; ++dc) {
    bf16x8 sf[4];
#pragma unroll
    for (int kc = 0; kc < 4; ++kc)
      sf[kc] = *(const bf16x8*)(Sb + ((size_t)(dc * 4 + kc) * 64 + lane) * 8);
#pragma unroll
    for (int kc = 0; kc < 4; ++kc)
      acc[dc] = __builtin_amdgcn_mfma_f32_16x16x32_bf16(xf[kc], sf[kc], acc[dc], 0, 0, 0);
  }

  __syncthreads();   // xbT complete (both waves)

  // trace partial (unscaled) + store Q pre-scaled by KE as bf16 in attn-frag layout
  float trp = 0.f;
#pragma unroll
  for (int dc = 0; dc < 8; ++dc)
#pragma unroll
    for (int r = 0; r < 4; ++r) {
      float q = acc[dc][r];
      float x = bf2f((unsigned short)xbT[(dc * 16 + c) * 32 + w * 16 + g * 4 + r]);
      trp += q * x;
      int t = tw + g * 4 + r;
      size_t qoff = (((size_t)(b * 64 + (t >> 5)) * 8 + dc) * 512 +
                     ((c >> 3) * 32 + (t & 31)) * 8 + (c & 7));
      Qb[qoff] = (unsigned short)cvt_pk_bf16(q * KE_CONST, 0.f);
    }

  // write Xt from xbT: 4 passes x 32 rows, b128 in / b128 out
#pragma unroll
  for (int p = 0; p < 4; ++p) {
    int row = p * 32 + (tid >> 2);
    bf16x8 v = *(const bf16x8*)&xbT[row * 32 + (tid & 3) * 8];
    *(bf16x8*)(Xt + ((size_t)(b * D_DIM + row)) * T_DIM + t0 + (tid & 3) * 8) = v;
  }

  // reduce trace partial: wave shuffle -> cross-wave via LDS
  trp += __shfl_xor(trp, 1); trp += __shfl_xor(trp, 2);
  trp += __shfl_xor(trp, 4); trp += __shfl_xor(trp, 8);
  trp += __shfl_xor(trp, 16); trp += __shfl_xor(trp, 32);
  if (lane == 0) red[w] = trp;
  __syncthreads();
  if (tid == 0) part[b * 64 + blockIdx.x] = red[0] + red[1];
}

// ---------------- Kernel C: flash attention — R13 schedule + ILP diet ----------------
// 4 waves x 32 t-rows, 512 blocks (2 blocks/CU). 2 LDS buffers, counted
// s_waitcnt vmcnt(4), 2 barriers/iter (R13-proven optimum). New this round:
// (1) QK^T split into two independent 4-deep MFMA chains (halves exposed
// latency at 2 waves/SIMD); (2) diag correction hoisted behind wave-uniform
// isd branch as p *= 2^(-ctrK); (3) raw v_exp_f32.
__global__ void __launch_bounds__(256, 2) k_attn(
    const unsigned short* __restrict__ Qb, const unsigned short* __restrict__ Xb,
    const unsigned short* __restrict__ Xt, const float* __restrict__ part,
    unsigned short* __restrict__ accp, float* __restrict__ rsp) {
  const int tid = threadIdx.x;
  const int wave = tid >> 6, lane = tid & 63;
  const int tl = lane & 31;      // C/D col = t-local; A row = s-local
  const int h = lane >> 5;       // half-wave -> k_local*8
  // XCD-aware decomposition: bid&7 == b pins batch b's working set to one XCD.
  const int lin = blockIdx.x;
  const int b = lin & 7;
  const int kk = lin >> 3;
  const int ns = kk & 3;
  const int tile = kk >> 2;                      // 0..15
  const int t0w = tile * 128 + wave * 32;        // 32 q-rows per wave

  const unsigned short* Xbb = Xb + (size_t)b * T_DIM * D_DIM;
  const unsigned short* Xtb = Xt + (size_t)b * D_DIM * T_DIM;

  // inline trace reduction (per-wave redundant, L2-hot)
  float tv = part[b * 64 + lane];
  tv += __shfl_xor(tv, 1); tv += __shfl_xor(tv, 2);
  tv += __shfl_xor(tv, 4); tv += __shfl_xor(tv, 8);
  tv += __shfl_xor(tv, 16); tv += __shfl_xor(tv, 32);
  const float ctrK = tv * (1.0f / T_DIM) * KE_CONST;
  const float expCtr = fexp2(-ctrK);   // diag correction as multiplier

  __shared__ __align__(16) short sKs[2][SBLK * D_DIM];   // 2 x 8 KB
  __shared__ __align__(16) short sVs[2][D_DIM * SBLK];   // 2 x 8 KB

  // swizzled ds_read offsets (shorts) — R11-verified
  int oK[8], oV[4][2];
#pragma unroll
  for (int kc = 0; kc < 8; ++kc)
    oK[kc] = tl * 128 + (((kc * 2 + h) ^ (tl & 15)) * 8);
#pragma unroll
  for (int dt = 0; dt < 4; ++dt)
#pragma unroll
    for (int sck = 0; sck < 2; ++sck)
      oV[dt][sck] = (dt * 32 + tl) * 32 + (((sck * 2 + h) ^ (tl & 3)) * 8);

  // Q B-frags, COALESCED from frag-layout Qb (R12-verified layout)
  const unsigned short* qbase =
      Qb + ((size_t)(b * 64 + tile * 4 + wave)) * 8 * 512;
  bf16x8 qf[8];
#pragma unroll
  for (int kc = 0; kc < 8; ++kc)
    qf[kc] = *(const bf16x8*)(qbase + (size_t)kc * 512 + lane * 8);

  f32x16 acc[4];
#pragma unroll
  for (int dt = 0; dt < 4; ++dt)
#pragma unroll
    for (int r = 0; r < 16; ++r) acc[dt][r] = 0.f;
  float denacc = 0.f;

  const int s_beg = ns * SCHUNK;

  // staging: 1024 16B chunks over 4 waves (2 K-issues + 2 V-issues per lane = 4 vmem)
  auto stage = [&](int buf, int sb) {
#pragma unroll
    for (int q = 0; q < 2; ++q) {
      int j = wave * 128 + q * 64 + lane;
      int row = j >> 4, sc = j & 15;
      int lc = sc ^ (row & 15);
      async16(&sKs[buf][(wave * 128 + q * 64) * 8],
              Xbb + (size_t)(sb + row) * D_DIM + lc * 8);
    }
#pragma unroll
    for (int q = 0; q < 2; ++q) {
      int j = wave * 128 + q * 64 + lane;
      int row = j >> 2, sc = j & 3;
      int lc = sc ^ (row & 3);
      async16(&sVs[buf][(wave * 128 + q * 64) * 8],
              Xtb + (size_t)row * T_DIM + sb + lc * 8);
    }
  };

  stage(0, s_beg);

  for (int it = 0; it < NIT; ++it) {
    const int buf = it & 1;
    const int sb = s_beg + it * SBLK;

    // issue next tile, then counted wait: own prior-tile (buf) issues complete,
    // the 4 just-issued (buf^1) stay in flight across the barrier.
    if (it < NIT - 1) {
      stage(buf ^ 1, sb + SBLK);
      asm volatile("s_waitcnt vmcnt(4)" ::: "memory");
    } else {
      asm volatile("s_waitcnt vmcnt(0)" ::: "memory");
    }
    __builtin_amdgcn_sched_barrier(0);
    __builtin_amdgcn_s_barrier();        // all waves: buf fully staged

    const short* kb = &sKs[buf][0];
    const short* vb = &sVs[buf][0];

    // LDS -> reg fragments (compiler inserts lgkmcnt before MFMA use)
    bf16x8 kf[8];
#pragma unroll
    for (int kc = 0; kc < 8; ++kc)
      kf[kc] = *(const bf16x8*)(kb + oK[kc]);
    bf16x8 vf[4][2];
#pragma unroll
    for (int dt = 0; dt < 4; ++dt)
#pragma unroll
      for (int sck = 0; sck < 2; ++sck)
        vf[dt][sck] = *(const bf16x8*)(vb + oV[dt][sck]);

    // ---- QK^T (swapped), TWO independent 4-deep chains -> merge ----
    f32x16 sa, sb2;
#pragma unroll
    for (int r = 0; r < 16; ++r) { sa[r] = 0.f; sb2[r] = 0.f; }
#pragma unroll
    for (int kc = 0; kc < 4; ++kc) {
      sa  = __builtin_amdgcn_mfma_f32_32x32x16_bf16(kf[kc],     qf[kc],     sa,  0, 0, 0);
      sb2 = __builtin_amdgcn_mfma_f32_32x32x16_bf16(kf[kc + 4], qf[kc + 4], sb2, 0, 0, 0);
    }
    f32x16 sc = sa + sb2;

    const bool isd = (sb == t0w);   // wave-uniform; both 32-aligned

    // ---- per s-chunk of 16: exp2 + in-register pack -> PV (R10-verified) ----
#pragma unroll
    for (int sck = 0; sck < 2; ++sck) {
      float p[8];
#pragma unroll
      for (int q = 0; q < 8; ++q) p[q] = fexp2(sc[sck * 8 + q]);
      if (isd) {   // wave-uniform branch: only the diagonal iteration
#pragma unroll
        for (int q = 0; q < 8; ++q) {
          int rowid = (q & 3) + 8 * (q >> 2) + 16 * sck + 4 * h;  // s_local
          if (rowid == tl) p[q] *= expCtr;
        }
      }
#pragma unroll
      for (int q = 0; q < 8; ++q) denacc += p[q];
      unsigned int W0 = cvt_pk_bf16(p[0], p[1]);
      unsigned int W1 = cvt_pk_bf16(p[2], p[3]);
      unsigned int W2 = cvt_pk_bf16(p[4], p[5]);
      unsigned int W3 = cvt_pk_bf16(p[6], p[7]);
      permswap(W0, W2);
      permswap(W1, W3);
      union PU { unsigned int wd[4]; bf16x8 v; } pu;
      pu.wd[0] = W0; pu.wd[1] = W1; pu.wd[2] = W2; pu.wd[3] = W3;
#pragma unroll
      for (int dt = 0; dt < 4; ++dt)
        acc[dt] = __builtin_amdgcn_mfma_f32_32x32x16_bf16(pu.v, vf[dt][sck],
                                                          acc[dt], 0, 0, 0);
    }

    // all waves done reading buf before anyone re-stages it next iteration
    __builtin_amdgcn_s_barrier();
  }

  // ---- den: own half + other half (same t, lane^32) ----
  float den = denacc + __shfl_xor(denacc, 32);
  if (lane < 32)
    rsp[(b * NS + ns) * T_DIM + t0w + lane] = den;

  // ---- write num partials (bf16), 32x32 C/D layout (R10-verified) ----
  const size_t pbase = ((size_t)(b * NS + ns)) * T_DIM * D_DIM;
#pragma unroll
  for (int dt = 0; dt < 4; ++dt)
#pragma unroll
    for (int r = 0; r < 16; ++r) {
      int rowid = (r & 3) + 8 * (r >> 2) + 4 * h;   // t_local
      accp[pbase + (size_t)(t0w + rowid) * D_DIM + dt * 32 + tl] =
          (unsigned short)cvt_pk_bf16(acc[dt][r], 0.f);
    }
}

// ---------------- Kernel D: combine split-K partials, 8 elems/thread, b128 ----------------
// XCD swizzle: bid&7 == b so accp/rsp reads hit the XCD-local L2.
__global__ void __launch_bounds__(256) k_comb(
    const unsigned short* __restrict__ accp, const float* __restrict__ rsp,
    float* __restrict__ out) {
  const int lin = blockIdx.x;
  const int b = lin & 7;
  const int kk = lin >> 3;                      // 0..127
  int ib = kk * 2048 + threadIdx.x * 8;         // element base within batch
  int d = ib & 127;
  int t = ib >> 7;
  float num[8] = {0.f, 0.f, 0.f, 0.f, 0.f, 0.f, 0.f, 0.f};
  float den = 0.f;
#pragma unroll
  for (int ns = 0; ns < NS; ++ns) {
    const unsigned short* p =
        accp + (((size_t)(b * NS + ns)) * T_DIM + t) * D_DIM + d;
    bf16x8 v = *(const bf16x8*)p;
#pragma unroll
    for (int j = 0; j < 8; ++j) num[j] += bf2f((unsigned short)v[j]);
    den += rsp[(b * NS + ns) * T_DIM + t];
  }
  float inv = 1.0f / den;
  float* o = out + ((size_t)b * T_DIM * D_DIM + ib);
  f32x4 o0 = (f32x4){num[0] * inv, num[1] * inv, num[2] * inv, num[3] * inv};
  f32x4 o1 = (f32x4){num[4] * inv, num[5] * inv, num[6] * inv, num[7] * inv};
  *(f32x4*)(o + 0) = o0;
  *(f32x4*)(o + 4) = o1;
}

extern "C" void kernel_launch(void* const* d_in, const int* in_sizes, int n_in,
                              void* d_out, int out_size, void* d_ws, size_t ws_size,
                              hipStream_t stream) {
  const float* X = (const float*)d_in[0];  // (8, 2048, 128) fp32
  const float* W = (const float*)d_in[1];  // (128, 64) fp32
  float* out = (float*)d_out;
  char* ws = (char*)d_ws;

  unsigned short* Sb = (unsigned short*)(ws);                 // 32 KB bf16 (frag layout)
  float* part        = (float*)(ws + 32768);                  // 2 KB
  unsigned short* Qb = (unsigned short*)(ws + 65536);         // 4 MB bf16 (frag layout)
  unsigned short* Xb = (unsigned short*)(ws + 65536 + 4194304);              // 4 MB
  unsigned short* Xt = (unsigned short*)(ws + 65536 + 2 * 4194304);          // 4 MB
  unsigned short* accp = (unsigned short*)(ws + 65536 + 3 * 4194304);        // 16 MB
  float* rsp         = (float*)(ws + 65536 + 3 * 4194304 + 16777216);        // 256 KB
  // total ws use: ~28.9 MB

  k_s<<<64, 256, 0, stream>>>(W, Sb);
  k_prep<<<dim3(T_DIM / 32, B_DIM), 128, 0, stream>>>(X, Sb, Qb, Xb, Xt, part);
  k_attn<<<(T_DIM / 128) * NS * B_DIM, 256, 0, stream>>>(Qb, Xb, Xt, part, accp, rsp);
  k_comb<<<B_DIM * 128, 256, 0, stream>>>(accp, rsp, out);
}